// Round 1
// baseline (6433.775 us; speedup 1.0000x reference)
//
#include <hip/hip_runtime.h>
#include <stdint.h>

#define BANDS 32
#define CHN   128
#define NPIX  4096
#define NTOT  16777216          // 32*128*4096
#define GSZ   16384             // 128*128
#define KSQ   6                 // squaring stages (G -> G^64, collapse-guarded)
#define QSTEPS 16               // subspace iteration steps

// ---------------- ws layout (float indices) ----------------
// bytes [0..168): doubles: [0]=sumW, [1..10]=lossF acc, [11..20]=loss acc
// floats [64..): per-band/ per-stage scalars
#define L_OFF    1024
#define GP_OFF   (L_OFF + NTOT)                  // 32*8*16384 gram partials
#define A0_OFF   (GP_OFF + BANDS*8*GSZ)
#define A1_OFF   (A0_OFF + BANDS*GSZ)
#define UTL_OFF  (A1_OFF + BANDS*GSZ)            // 32*3*4096
#define U3_OFF   (UTL_OFF + BANDS*3*NPIX)        // 32*128*3
#define VW_OFF   (U3_OFF + BANDS*CHN*3)          // 32*128*8 warm-start basis

__device__ __forceinline__ int FRO2I(int st, int b){ return 64  + st*32 + b; }
__device__ __forceinline__ int TRI  (int st, int b){ return 300 + st*32 + b; }
__device__ __forceinline__ int FLAGI(int st, int b){ return 540 + st*32 + b; }

// ---------------- init: L = x, sumW reduction ----------------
__global__ __launch_bounds__(256) void k_init(const float* __restrict__ x,
                                              const float* __restrict__ W,
                                              float* __restrict__ ws) {
    int gid = blockIdx.x * 256 + threadIdx.x;       // 2048*256 threads
    const float4* x4 = (const float4*)x;
    const float4* w4 = (const float4*)W;
    float4* L4 = (float4*)(ws + L_OFF);
    float s = 0.f;
#pragma unroll
    for (int i = 0; i < 8; i++) {
        int idx = gid + i * 524288;                 // NTOT/4 = 4194304
        float4 xv = x4[idx];
        float4 wv = w4[idx];
        L4[idx] = xv;
        s += wv.x + wv.y + wv.z + wv.w;
    }
    for (int o = 32; o > 0; o >>= 1) s += __shfl_down(s, o, 64);
    __shared__ float red[4];
    int wid = threadIdx.x >> 6, lane = threadIdx.x & 63;
    if (lane == 0) red[wid] = s;
    __syncthreads();
    if (threadIdx.x == 0) {
        float t = red[0] + red[1] + red[2] + red[3];
        atomicAdd((double*)ws, (double)t);
    }
}

// ---------------- gram: partial G[b] = L L^T, split-K 8 ----------------
__global__ __launch_bounds__(256) void k_gram(float* __restrict__ ws) {
    int band = blockIdx.y, kc = blockIdx.x, tid = threadIdx.x;
    if (kc == 0) {   // zero stage-0 scalars for the reduce kernel's atomics
        if (tid == 0) ws[FRO2I(0, band)] = 0.f;
        if (tid == 1) ws[TRI(0, band)]   = 0.f;
        if (tid == 2) ws[FLAGI(0, band)] = 0.f;
    }
    __shared__ __align__(16) float Lt[16][132];     // [kk][c], padded
    const float* Lb = ws + L_OFF + (size_t)band * CHN * NPIX;
    int k0 = kc * 512;
    int ty = tid >> 4, tx = tid & 15;
    float acc[8][8];
#pragma unroll
    for (int i = 0; i < 8; i++)
#pragma unroll
        for (int j = 0; j < 8; j++) acc[i][j] = 0.f;

    int lc = tid >> 1, lk = (tid & 1) * 8;
    for (int t = 0; t < 32; t++) {
        int kb = k0 + t * 16;
        const float* src = Lb + (size_t)lc * NPIX + kb + lk;
        float4 v0 = *(const float4*)(src);
        float4 v1 = *(const float4*)(src + 4);
        __syncthreads();
        Lt[lk + 0][lc] = v0.x; Lt[lk + 1][lc] = v0.y;
        Lt[lk + 2][lc] = v0.z; Lt[lk + 3][lc] = v0.w;
        Lt[lk + 4][lc] = v1.x; Lt[lk + 5][lc] = v1.y;
        Lt[lk + 6][lc] = v1.z; Lt[lk + 7][lc] = v1.w;
        __syncthreads();
#pragma unroll
        for (int kk = 0; kk < 16; kk++) {
            float4 a0 = *(const float4*)&Lt[kk][ty * 8];
            float4 a1 = *(const float4*)&Lt[kk][ty * 8 + 4];
            float4 b0 = *(const float4*)&Lt[kk][tx * 8];
            float4 b1 = *(const float4*)&Lt[kk][tx * 8 + 4];
            float a[8] = {a0.x,a0.y,a0.z,a0.w,a1.x,a1.y,a1.z,a1.w};
            float b[8] = {b0.x,b0.y,b0.z,b0.w,b1.x,b1.y,b1.z,b1.w};
#pragma unroll
            for (int i = 0; i < 8; i++)
#pragma unroll
                for (int j = 0; j < 8; j++) acc[i][j] += a[i] * b[j];
        }
    }
    float* Gp = ws + GP_OFF + (size_t)(band * 8 + kc) * GSZ;
#pragma unroll
    for (int i = 0; i < 8; i++) {
        int row = ty * 8 + i;
        *(float4*)&Gp[row * 128 + tx * 8]     = make_float4(acc[i][0], acc[i][1], acc[i][2], acc[i][3]);
        *(float4*)&Gp[row * 128 + tx * 8 + 4] = make_float4(acc[i][4], acc[i][5], acc[i][6], acc[i][7]);
    }
}

// ---------------- reduceG: sum partials -> A0, stage-0 stats ----------------
__global__ __launch_bounds__(256) void k_reduceG(float* __restrict__ ws) {
    int band = blockIdx.y, xc = blockIdx.x, tid = threadIdx.x;
    if (xc == 0 && tid < 18) {          // zero stage 1..6 scalars
        int st = 1 + tid / 3, a = tid % 3;
        int off = (a == 0) ? FRO2I(st, band) : (a == 1) ? TRI(st, band) : FLAGI(st, band);
        ws[off] = 0.f;
    }
    int e0 = xc * 2048 + tid * 8;
    float v[8];
#pragma unroll
    for (int j = 0; j < 8; j++) v[j] = 0.f;
#pragma unroll
    for (int p = 0; p < 8; p++) {
        const float4* src = (const float4*)(ws + GP_OFF + (size_t)(band * 8 + p) * GSZ + e0);
        float4 s0 = src[0], s1 = src[1];
        v[0] += s0.x; v[1] += s0.y; v[2] += s0.z; v[3] += s0.w;
        v[4] += s1.x; v[5] += s1.y; v[6] += s1.z; v[7] += s1.w;
    }
    float4* dst = (float4*)(ws + A0_OFF + (size_t)band * GSZ + e0);
    dst[0] = make_float4(v[0], v[1], v[2], v[3]);
    dst[1] = make_float4(v[4], v[5], v[6], v[7]);
    float fp = 0.f, tp = 0.f;
    int row = e0 >> 7, col0 = e0 & 127;
#pragma unroll
    for (int j = 0; j < 8; j++) {
        fp += v[j] * v[j];
        if (col0 + j == row) tp += v[j];
    }
    for (int o = 32; o > 0; o >>= 1) { fp += __shfl_down(fp, o, 64); tp += __shfl_down(tp, o, 64); }
    __shared__ float red[16];
    int wid = tid >> 6, lane = tid & 63;
    if (lane == 0) { red[wid] = fp; red[8 + wid] = tp; }
    __syncthreads();
    if (tid == 0) {
        atomicAdd(&ws[FRO2I(0, band)], red[0] + red[1] + red[2] + red[3]);
        atomicAdd(&ws[TRI(0, band)],   red[8] + red[9] + red[10] + red[11]);
    }
}

// ---------------- sq: B = (A/||A||_F)^2 with collapse guard ----------------
__global__ __launch_bounds__(256) void k_sq(float* __restrict__ ws, int inOff, int outOff, int stage) {
    __shared__ __align__(16) float As[16384];       // 64 KB exactly (reused as reduce scratch)
    int band = blockIdx.y, rb = blockIdx.x * 32, tid = threadIdx.x;
    const float* Ain = ws + inOff + (size_t)band * GSZ;
    float* Bout = ws + outOff + (size_t)band * GSZ;
    float fro2 = ws[FRO2I(stage, band)];
    float tr   = ws[TRI(stage, band)];
    float flag = ws[FLAGI(stage, band)];
    bool collapsed = (flag > 0.5f) || (tr * tr < 3.5f * fro2);
    float fp = 0.f, tp = 0.f;

    if (collapsed) {
        int base = rb * 128;
#pragma unroll
        for (int r = 0; r < 4; r++) {
            int fi = base + (tid + r * 256) * 4;
            float4 v = *(const float4*)(Ain + fi);
            *(float4*)(Bout + fi) = v;
            fp += v.x*v.x + v.y*v.y + v.z*v.z + v.w*v.w;
            int row = fi >> 7, col0 = fi & 127, e = row - col0;
            if (e >= 0 && e < 4) tp += (&v.x)[e];
        }
    } else {
        float scale = rsqrtf(fro2 + 1e-30f);
        const float4* Ain4 = (const float4*)Ain;
        float4* As4 = (float4*)As;
#pragma unroll
        for (int rep = 0; rep < 16; rep++) {
            int fi4 = rep * 256 + tid;              // float4 index
            int c = fi4 >> 5, g = fi4 & 31;
            float4 v = Ain4[fi4];
            v.x *= scale; v.y *= scale; v.z *= scale; v.w *= scale;
            As4[c * 32 + (g ^ (c >> 2))] = v;
        }
        __syncthreads();
        int tyy = tid >> 5, txx = tid & 31;
        int r0 = rb + tyy * 4, c0 = txx * 4;
        int rsh = r0 >> 2, csh = c0 >> 2;
        float acc[4][4];
#pragma unroll
        for (int i = 0; i < 4; i++)
#pragma unroll
            for (int j = 0; j < 4; j++) acc[i][j] = 0.f;
#pragma unroll 4
        for (int g = 0; g < 32; g++) {
            float4 a[4], b[4];
            int ga = g ^ rsh, gb = g ^ csh;
#pragma unroll
            for (int i = 0; i < 4; i++) a[i] = As4[(r0 + i) * 32 + ga];
#pragma unroll
            for (int j = 0; j < 4; j++) b[j] = As4[(c0 + j) * 32 + gb];
#pragma unroll
            for (int i = 0; i < 4; i++)
#pragma unroll
                for (int j = 0; j < 4; j++)
                    acc[i][j] += a[i].x*b[j].x + a[i].y*b[j].y + a[i].z*b[j].z + a[i].w*b[j].w;
        }
        __syncthreads();    // done reading As; safe to reuse as scratch below
#pragma unroll
        for (int i = 0; i < 4; i++) {
            int row = r0 + i;
            *(float4*)&Bout[row * 128 + c0] = make_float4(acc[i][0], acc[i][1], acc[i][2], acc[i][3]);
#pragma unroll
            for (int j = 0; j < 4; j++) {
                fp += acc[i][j] * acc[i][j];
                if (row == c0 + j) tp += acc[i][j];
            }
        }
    }
    for (int o = 32; o > 0; o >>= 1) { fp += __shfl_down(fp, o, 64); tp += __shfl_down(tp, o, 64); }
    int wid = tid >> 6, lane = tid & 63;
    __syncthreads();
    if (lane == 0) { As[wid] = fp; As[8 + wid] = tp; }
    __syncthreads();
    if (tid == 0) {
        atomicAdd(&ws[FRO2I(stage + 1, band)], As[0] + As[1] + As[2] + As[3]);
        atomicAdd(&ws[TRI(stage + 1, band)],   As[8] + As[9] + As[10] + As[11]);
        if (blockIdx.x == 0) ws[FLAGI(stage + 1, band)] = collapsed ? 1.f : 0.f;
    }
}

// ---------------- subspace iteration + Rayleigh-Ritz ----------------
__global__ __launch_bounds__(256) void k_sub(float* __restrict__ ws, int titer) {
    int band = blockIdx.x, tid = threadIdx.x;
    const float* Ab = ws + A0_OFF + (size_t)band * GSZ;
    __shared__ __align__(16) float Vl[128][8];
    __shared__ __align__(16) float Wl[128][8];
    __shared__ float Mm[64], Lch[64], invd[8], B8[64], E8[64];
    __shared__ int idx3[3];

    if (titer == 0) {
        for (int idx = tid; idx < 1024; idx += 256) {
            uint32_t h = (uint32_t)(idx + band * 1024 + 7) * 2654435761u;
            h ^= h >> 15; h *= 0x2c1b3c6du; h ^= h >> 12;
            Vl[idx >> 3][idx & 7] = ((float)(h & 0xFFFF) / 32768.0f) - 1.0f;
        }
    } else {
        for (int idx = tid; idx < 1024; idx += 256)
            Vl[idx >> 3][idx & 7] = ws[VW_OFF + band * 1024 + idx];
    }
    __syncthreads();

    int c = tid & 127, sq = tid >> 7;
    for (int step = 0; step <= QSTEPS; step++) {
        // W = A * V  (A symmetric; row reads, V broadcast from LDS)
        {
            const float4* Arow4 = (const float4*)(Ab + c * 128);
            float4 acc = make_float4(0.f, 0.f, 0.f, 0.f);
#pragma unroll 8
            for (int g = 0; g < 32; g++) {
                float4 a4 = Arow4[g];
                const float* vb = &Vl[g * 4][sq * 4];
                float4 v0 = *(const float4*)(vb);
                float4 v1 = *(const float4*)(vb + 8);
                float4 v2 = *(const float4*)(vb + 16);
                float4 v3 = *(const float4*)(vb + 24);
                acc.x += a4.x*v0.x + a4.y*v1.x + a4.z*v2.x + a4.w*v3.x;
                acc.y += a4.x*v0.y + a4.y*v1.y + a4.z*v2.y + a4.w*v3.y;
                acc.z += a4.x*v0.z + a4.y*v1.z + a4.z*v2.z + a4.w*v3.z;
                acc.w += a4.x*v0.w + a4.y*v1.w + a4.z*v2.w + a4.w*v3.w;
            }
            *(float4*)&Wl[c][sq * 4] = acc;
        }
        __syncthreads();
        if (step == QSTEPS) break;
        // CholQR: M = W^T W
        if (tid < 64) {
            int r = tid >> 3, s = tid & 7;
            float m = 0.f;
            for (int cc = 0; cc < 128; cc++) m += Wl[cc][r] * Wl[cc][s];
            Mm[r * 8 + s] = m;
        }
        __syncthreads();
        if (tid == 0) {
            float trM = Mm[0] + Mm[9] + Mm[18] + Mm[27] + Mm[36] + Mm[45] + Mm[54] + Mm[63];
            float eps = 1e-12f * trM + 1e-35f;
            for (int j = 0; j < 8; j++) {
                float d = Mm[j * 8 + j];
                for (int k = 0; k < j; k++) d -= Lch[j * 8 + k] * Lch[j * 8 + k];
                d = fmaxf(d, eps);
                float lj = sqrtf(d);
                Lch[j * 8 + j] = lj;
                float inv = 1.f / lj;
                invd[j] = inv;
                for (int i = j + 1; i < 8; i++) {
                    float v2 = Mm[i * 8 + j];
                    for (int k = 0; k < j; k++) v2 -= Lch[i * 8 + k] * Lch[j * 8 + k];
                    Lch[i * 8 + j] = v2 * inv;
                }
            }
        }
        __syncthreads();
        if (tid < 128) {
            float w[8], v[8];
#pragma unroll
            for (int s = 0; s < 8; s++) w[s] = Wl[tid][s];
#pragma unroll
            for (int s = 0; s < 8; s++) {
                float vv = w[s];
                for (int j = 0; j < s; j++) vv -= v[j] * Lch[s * 8 + j];
                v[s] = vv * invd[s];
                Vl[tid][s] = v[s];
            }
        }
        __syncthreads();
    }
    // Rayleigh-Ritz: B8 = V^T (A V)
    if (tid < 64) {
        int r = tid >> 3, s = tid & 7;
        float m = 0.f;
        for (int cc = 0; cc < 128; cc++) m += Vl[cc][r] * Wl[cc][s];
        B8[r * 8 + s] = m;
    }
    __syncthreads();
    if (tid == 0) {
        for (int i = 0; i < 8; i++)
            for (int j = i + 1; j < 8; j++) {
                float m = 0.5f * (B8[i * 8 + j] + B8[j * 8 + i]);
                B8[i * 8 + j] = m; B8[j * 8 + i] = m;
            }
        for (int i = 0; i < 8; i++)
            for (int j = 0; j < 8; j++) E8[i * 8 + j] = (i == j) ? 1.f : 0.f;
        for (int sw = 0; sw < 8; sw++)
            for (int p = 0; p < 7; p++)
                for (int q = p + 1; q < 8; q++) {
                    float apq = B8[p * 8 + q];
                    if (fabsf(apq) < 1e-30f) continue;
                    float app = B8[p * 8 + p], aqq = B8[q * 8 + q];
                    float tau = (aqq - app) / (2.f * apq);
                    float tt = ((tau >= 0.f) ? 1.f : -1.f) / (fabsf(tau) + sqrtf(1.f + tau * tau));
                    float cc = rsqrtf(1.f + tt * tt);
                    float ss = tt * cc;
                    for (int k = 0; k < 8; k++) {
                        float bpk = B8[p * 8 + k], bqk = B8[q * 8 + k];
                        B8[p * 8 + k] = cc * bpk - ss * bqk;
                        B8[q * 8 + k] = ss * bpk + cc * bqk;
                    }
                    for (int k = 0; k < 8; k++) {
                        float bkp = B8[k * 8 + p], bkq = B8[k * 8 + q];
                        B8[k * 8 + p] = cc * bkp - ss * bkq;
                        B8[k * 8 + q] = ss * bkp + cc * bkq;
                    }
                    for (int k = 0; k < 8; k++) {
                        float ekp = E8[k * 8 + p], ekq = E8[k * 8 + q];
                        E8[k * 8 + p] = cc * ekp - ss * ekq;
                        E8[k * 8 + q] = ss * ekp + cc * ekq;
                    }
                }
        // top-3 eigenvalue indices
        int used = 0;
        for (int r = 0; r < 3; r++) {
            int best = -1; float bv = -1e38f;
            for (int s = 0; s < 8; s++)
                if (!(used & (1 << s)) && B8[s * 8 + s] > bv) { bv = B8[s * 8 + s]; best = s; }
            used |= 1 << best;
            idx3[r] = best;
        }
    }
    __syncthreads();
    if (tid < 128) {
        int cc = tid;
        for (int r = 0; r < 3; r++) {
            float u = 0.f;
#pragma unroll
            for (int s = 0; s < 8; s++) u += Vl[cc][s] * E8[s * 8 + idx3[r]];
            ws[U3_OFF + band * 384 + cc * 3 + r] = u;
        }
#pragma unroll
        for (int s = 0; s < 8; s++) ws[VW_OFF + band * 1024 + cc * 8 + s] = Vl[cc][s];
    }
}

// ---------------- UtL = U^T L ----------------
__global__ __launch_bounds__(256) void k_utl(float* __restrict__ ws) {
    int band = blockIdx.y, xc = blockIdx.x, tid = threadIdx.x;
    __shared__ float Ul[128][3];
    if (tid < 128) {
        Ul[tid][0] = ws[U3_OFF + band * 384 + tid * 3 + 0];
        Ul[tid][1] = ws[U3_OFF + band * 384 + tid * 3 + 1];
        Ul[tid][2] = ws[U3_OFF + band * 384 + tid * 3 + 2];
    }
    __syncthreads();
    int n0 = xc * 512;
    const float* Lb = ws + L_OFF + (size_t)band * CHN * NPIX;
    float a0 = 0, a1 = 0, a2 = 0, b0 = 0, b1 = 0, b2 = 0;
    for (int cc = 0; cc < 128; cc++) {
        float u0 = Ul[cc][0], u1 = Ul[cc][1], u2 = Ul[cc][2];
        float la = Lb[(size_t)cc * NPIX + n0 + tid];
        float lb = Lb[(size_t)cc * NPIX + n0 + 256 + tid];
        a0 += u0 * la; a1 += u1 * la; a2 += u2 * la;
        b0 += u0 * lb; b1 += u1 * lb; b2 += u2 * lb;
    }
    float* UtL = ws + UTL_OFF + (size_t)band * 3 * NPIX;
    UtL[0 * NPIX + n0 + tid] = a0;
    UtL[1 * NPIX + n0 + tid] = a1;
    UtL[2 * NPIX + n0 + tid] = a2;
    UtL[0 * NPIX + n0 + 256 + tid] = b0;
    UtL[1 * NPIX + n0 + 256 + tid] = b1;
    UtL[2 * NPIX + n0 + 256 + tid] = b2;
}

// ---------------- update: UV, losses, L_new ----------------
__global__ __launch_bounds__(256) void k_update(const float* __restrict__ x,
                                                const float* __restrict__ W,
                                                const float* __restrict__ xg,
                                                float* __restrict__ out,
                                                float* __restrict__ ws,
                                                float alphapow, int writeUV, int titer) {
    int gid = blockIdx.x * 256 + threadIdx.x;   // 8192*256
    int i0 = gid * 8;
    int band = i0 >> 19;
    int crow = (i0 >> 12) & 127;
    int n0 = i0 & 4095;
    double sw = *(const double*)ws;
    float rho = 0.5f * (float)(sw / (double)NTOT) * alphapow;

    const float* UtL = ws + UTL_OFF + (size_t)band * 3 * NPIX;
    float u0 = ws[U3_OFF + band * 384 + crow * 3 + 0];
    float u1 = ws[U3_OFF + band * 384 + crow * 3 + 1];
    float u2 = ws[U3_OFF + band * 384 + crow * 3 + 2];

    float xv[8], wv[8], gv[8], t0[8], t1[8], t2[8];
    *(float4*)&xv[0] = *(const float4*)(x + i0);     *(float4*)&xv[4] = *(const float4*)(x + i0 + 4);
    *(float4*)&wv[0] = *(const float4*)(W + i0);     *(float4*)&wv[4] = *(const float4*)(W + i0 + 4);
    *(float4*)&gv[0] = *(const float4*)(xg + i0);    *(float4*)&gv[4] = *(const float4*)(xg + i0 + 4);
    *(float4*)&t0[0] = *(const float4*)(UtL + n0);            *(float4*)&t0[4] = *(const float4*)(UtL + n0 + 4);
    *(float4*)&t1[0] = *(const float4*)(UtL + NPIX + n0);     *(float4*)&t1[4] = *(const float4*)(UtL + NPIX + n0 + 4);
    *(float4*)&t2[0] = *(const float4*)(UtL + 2 * NPIX + n0); *(float4*)&t2[4] = *(const float4*)(UtL + 2 * NPIX + n0 + 4);

    float lf = 0.f, ll = 0.f;
    float ln[8], uvv[8];
#pragma unroll
    for (int e = 0; e < 8; e++) {
        float uv = u0 * t0[e] + u1 * t1[e] + u2 * t2[e];
        uvv[e] = uv;
        float d = uv - xv[e];
        lf += wv[e] * d * d;
        float dg = uv - gv[e];
        ll += dg * dg;
        float mu = rho / (wv[e] + rho);
        ln[e] = xv[e] + mu * d;
    }
    float* Lp = ws + L_OFF;
    *(float4*)(Lp + i0)     = *(float4*)&ln[0];
    *(float4*)(Lp + i0 + 4) = *(float4*)&ln[4];
    if (writeUV) {
        *(float4*)(out + i0)     = *(float4*)&uvv[0];
        *(float4*)(out + i0 + 4) = *(float4*)&uvv[4];
    }
    for (int o = 32; o > 0; o >>= 1) { lf += __shfl_down(lf, o, 64); ll += __shfl_down(ll, o, 64); }
    __shared__ float red[16];
    int wid = threadIdx.x >> 6, lane = threadIdx.x & 63;
    if (lane == 0) { red[wid] = lf; red[8 + wid] = ll; }
    __syncthreads();
    if (threadIdx.x == 0) {
        float a = red[0] + red[1] + red[2] + red[3];
        float b = red[8] + red[9] + red[10] + red[11];
        atomicAdd((double*)ws + 1 + titer,  (double)a);
        atomicAdd((double*)ws + 11 + titer, (double)b);
    }
}

// ---------------- finalize losses ----------------
__global__ void k_final(float* __restrict__ out, const float* __restrict__ ws) {
    int tid = threadIdx.x;
    const double* d = (const double*)ws;
    if (tid < 10)       out[NTOT + tid] = (float)(d[1 + tid] / (double)NTOT);
    else if (tid < 20)  out[NTOT + tid] = (float)(d[11 + (tid - 10)] / (double)NTOT);
}

extern "C" void kernel_launch(void* const* d_in, const int* in_sizes, int n_in,
                              void* d_out, int out_size, void* d_ws, size_t ws_size,
                              hipStream_t stream) {
    const float* x  = (const float*)d_in[0];
    const float* W  = (const float*)d_in[1];
    const float* xg = (const float*)d_in[2];
    float* out = (float*)d_out;
    float* ws = (float*)d_ws;

    hipMemsetAsync(d_ws, 0, 4096, stream);   // zero scalar/accumulator block
    k_init<<<2048, 256, 0, stream>>>(x, W, ws);

    float ap = 1.0f;
    for (int t = 0; t < 10; t++) {
        k_gram<<<dim3(8, 32), 256, 0, stream>>>(ws);
        k_reduceG<<<dim3(8, 32), 256, 0, stream>>>(ws);
        for (int j = 0; j < KSQ; j++) {
            int inOff  = (j & 1) ? A1_OFF : A0_OFF;
            int outOff = (j & 1) ? A0_OFF : A1_OFF;
            k_sq<<<dim3(4, 32), 256, 0, stream>>>(ws, inOff, outOff, j);
        }
        k_sub<<<32, 256, 0, stream>>>(ws, t);
        k_utl<<<dim3(8, 32), 256, 0, stream>>>(ws);
        k_update<<<8192, 256, 0, stream>>>(x, W, xg, out, ws, ap, (t == 9) ? 1 : 0, t);
        ap *= 1.05f;
    }
    k_final<<<1, 64, 0, stream>>>(out, ws);
}

// Round 2
// 3566.014 us; speedup vs baseline: 1.8042x; 1.8042x over previous
//
#include <hip/hip_runtime.h>
#include <stdint.h>

#define BANDS 32
#define CHN   128
#define NPIX  4096
#define NTOT  16777216          // 32*128*4096
#define GSZ   16384             // 128*128
#define KSQ   6                 // squaring stages (G -> G^64, collapse-guarded)

// ---------------- ws layout (float indices) ----------------
// bytes [0..168): doubles: [0]=sumW, [1..10]=lossF acc, [11..20]=loss acc
// floats [64..): per-band/ per-stage scalars
#define L_OFF    1024
#define GP_OFF   (L_OFF + NTOT)                  // 32*8*16384 gram partials
#define A0_OFF   (GP_OFF + BANDS*8*GSZ)
#define A1_OFF   (A0_OFF + BANDS*GSZ)
#define UTL_OFF  (A1_OFF + BANDS*GSZ)            // 32*3*4096
#define U3_OFF   (UTL_OFF + BANDS*3*NPIX)        // 32*128*3
#define VW_OFF   (U3_OFF + BANDS*CHN*3)          // 32*128*8 warm-start basis

__device__ __forceinline__ int FRO2I(int st, int b){ return 64  + st*32 + b; }
__device__ __forceinline__ int TRI  (int st, int b){ return 300 + st*32 + b; }
__device__ __forceinline__ int FLAGI(int st, int b){ return 540 + st*32 + b; }

// ---------------- init: L = x, sumW reduction ----------------
__global__ __launch_bounds__(256) void k_init(const float* __restrict__ x,
                                              const float* __restrict__ W,
                                              float* __restrict__ ws) {
    int gid = blockIdx.x * 256 + threadIdx.x;       // 2048*256 threads
    const float4* x4 = (const float4*)x;
    const float4* w4 = (const float4*)W;
    float4* L4 = (float4*)(ws + L_OFF);
    float s = 0.f;
#pragma unroll
    for (int i = 0; i < 8; i++) {
        int idx = gid + i * 524288;                 // NTOT/4 = 4194304
        float4 xv = x4[idx];
        float4 wv = w4[idx];
        L4[idx] = xv;
        s += wv.x + wv.y + wv.z + wv.w;
    }
    for (int o = 32; o > 0; o >>= 1) s += __shfl_down(s, o, 64);
    __shared__ float red[4];
    int wid = threadIdx.x >> 6, lane = threadIdx.x & 63;
    if (lane == 0) red[wid] = s;
    __syncthreads();
    if (threadIdx.x == 0) {
        float t = red[0] + red[1] + red[2] + red[3];
        atomicAdd((double*)ws, (double)t);
    }
}

// ---------------- gram: partial G[b] = L L^T, split-K 8 ----------------
__global__ __launch_bounds__(256) void k_gram(float* __restrict__ ws) {
    int band = blockIdx.y, kc = blockIdx.x, tid = threadIdx.x;
    if (kc == 0) {   // zero stage-0 scalars for the reduce kernel's atomics
        if (tid == 0) ws[FRO2I(0, band)] = 0.f;
        if (tid == 1) ws[TRI(0, band)]   = 0.f;
        if (tid == 2) ws[FLAGI(0, band)] = 0.f;
    }
    __shared__ __align__(16) float Lt[16][132];     // [kk][c], padded
    const float* Lb = ws + L_OFF + (size_t)band * CHN * NPIX;
    int k0 = kc * 512;
    int ty = tid >> 4, tx = tid & 15;
    float acc[8][8];
#pragma unroll
    for (int i = 0; i < 8; i++)
#pragma unroll
        for (int j = 0; j < 8; j++) acc[i][j] = 0.f;

    int lc = tid >> 1, lk = (tid & 1) * 8;
    for (int t = 0; t < 32; t++) {
        int kb = k0 + t * 16;
        const float* src = Lb + (size_t)lc * NPIX + kb + lk;
        float4 v0 = *(const float4*)(src);
        float4 v1 = *(const float4*)(src + 4);
        __syncthreads();
        Lt[lk + 0][lc] = v0.x; Lt[lk + 1][lc] = v0.y;
        Lt[lk + 2][lc] = v0.z; Lt[lk + 3][lc] = v0.w;
        Lt[lk + 4][lc] = v1.x; Lt[lk + 5][lc] = v1.y;
        Lt[lk + 6][lc] = v1.z; Lt[lk + 7][lc] = v1.w;
        __syncthreads();
#pragma unroll
        for (int kk = 0; kk < 16; kk++) {
            float4 a0 = *(const float4*)&Lt[kk][ty * 8];
            float4 a1 = *(const float4*)&Lt[kk][ty * 8 + 4];
            float4 b0 = *(const float4*)&Lt[kk][tx * 8];
            float4 b1 = *(const float4*)&Lt[kk][tx * 8 + 4];
            float a[8] = {a0.x,a0.y,a0.z,a0.w,a1.x,a1.y,a1.z,a1.w};
            float b[8] = {b0.x,b0.y,b0.z,b0.w,b1.x,b1.y,b1.z,b1.w};
#pragma unroll
            for (int i = 0; i < 8; i++)
#pragma unroll
                for (int j = 0; j < 8; j++) acc[i][j] += a[i] * b[j];
        }
    }
    float* Gp = ws + GP_OFF + (size_t)(band * 8 + kc) * GSZ;
#pragma unroll
    for (int i = 0; i < 8; i++) {
        int row = ty * 8 + i;
        *(float4*)&Gp[row * 128 + tx * 8]     = make_float4(acc[i][0], acc[i][1], acc[i][2], acc[i][3]);
        *(float4*)&Gp[row * 128 + tx * 8 + 4] = make_float4(acc[i][4], acc[i][5], acc[i][6], acc[i][7]);
    }
}

// ---------------- reduceG: sum partials -> A0, stage-0 stats ----------------
__global__ __launch_bounds__(256) void k_reduceG(float* __restrict__ ws) {
    int band = blockIdx.y, xc = blockIdx.x, tid = threadIdx.x;
    if (xc == 0 && tid < 18) {          // zero stage 1..6 scalars
        int st = 1 + tid / 3, a = tid % 3;
        int off = (a == 0) ? FRO2I(st, band) : (a == 1) ? TRI(st, band) : FLAGI(st, band);
        ws[off] = 0.f;
    }
    int e0 = xc * 2048 + tid * 8;
    float v[8];
#pragma unroll
    for (int j = 0; j < 8; j++) v[j] = 0.f;
#pragma unroll
    for (int p = 0; p < 8; p++) {
        const float4* src = (const float4*)(ws + GP_OFF + (size_t)(band * 8 + p) * GSZ + e0);
        float4 s0 = src[0], s1 = src[1];
        v[0] += s0.x; v[1] += s0.y; v[2] += s0.z; v[3] += s0.w;
        v[4] += s1.x; v[5] += s1.y; v[6] += s1.z; v[7] += s1.w;
    }
    float4* dst = (float4*)(ws + A0_OFF + (size_t)band * GSZ + e0);
    dst[0] = make_float4(v[0], v[1], v[2], v[3]);
    dst[1] = make_float4(v[4], v[5], v[6], v[7]);
    float fp = 0.f, tp = 0.f;
    int row = e0 >> 7, col0 = e0 & 127;
#pragma unroll
    for (int j = 0; j < 8; j++) {
        fp += v[j] * v[j];
        if (col0 + j == row) tp += v[j];
    }
    for (int o = 32; o > 0; o >>= 1) { fp += __shfl_down(fp, o, 64); tp += __shfl_down(tp, o, 64); }
    __shared__ float red[16];
    int wid = tid >> 6, lane = tid & 63;
    if (lane == 0) { red[wid] = fp; red[8 + wid] = tp; }
    __syncthreads();
    if (tid == 0) {
        atomicAdd(&ws[FRO2I(0, band)], red[0] + red[1] + red[2] + red[3]);
        atomicAdd(&ws[TRI(0, band)],   red[8] + red[9] + red[10] + red[11]);
    }
}

// ---------------- sq: B = (A/||A||_F)^2 with collapse guard ----------------
__global__ __launch_bounds__(256) void k_sq(float* __restrict__ ws, int inOff, int outOff, int stage) {
    __shared__ __align__(16) float As[16384];       // 64 KB exactly (reused as reduce scratch)
    int band = blockIdx.y, rb = blockIdx.x * 32, tid = threadIdx.x;
    const float* Ain = ws + inOff + (size_t)band * GSZ;
    float* Bout = ws + outOff + (size_t)band * GSZ;
    float fro2 = ws[FRO2I(stage, band)];
    float tr   = ws[TRI(stage, band)];
    float flag = ws[FLAGI(stage, band)];
    bool collapsed = (flag > 0.5f) || (tr * tr < 3.5f * fro2);
    float fp = 0.f, tp = 0.f;

    if (collapsed) {
        int base = rb * 128;
#pragma unroll
        for (int r = 0; r < 4; r++) {
            int fi = base + (tid + r * 256) * 4;
            float4 v = *(const float4*)(Ain + fi);
            *(float4*)(Bout + fi) = v;
            fp += v.x*v.x + v.y*v.y + v.z*v.z + v.w*v.w;
            int row = fi >> 7, col0 = fi & 127, e = row - col0;
            if (e >= 0 && e < 4) tp += (&v.x)[e];
        }
    } else {
        float scale = rsqrtf(fro2 + 1e-30f);
        const float4* Ain4 = (const float4*)Ain;
        float4* As4 = (float4*)As;
#pragma unroll
        for (int rep = 0; rep < 16; rep++) {
            int fi4 = rep * 256 + tid;              // float4 index
            int c = fi4 >> 5, g = fi4 & 31;
            float4 v = Ain4[fi4];
            v.x *= scale; v.y *= scale; v.z *= scale; v.w *= scale;
            As4[c * 32 + (g ^ (c >> 2))] = v;
        }
        __syncthreads();
        int tyy = tid >> 5, txx = tid & 31;
        int r0 = rb + tyy * 4, c0 = txx * 4;
        int rsh = r0 >> 2, csh = c0 >> 2;
        float acc[4][4];
#pragma unroll
        for (int i = 0; i < 4; i++)
#pragma unroll
            for (int j = 0; j < 4; j++) acc[i][j] = 0.f;
#pragma unroll 4
        for (int g = 0; g < 32; g++) {
            float4 a[4], b[4];
            int ga = g ^ rsh, gb = g ^ csh;
#pragma unroll
            for (int i = 0; i < 4; i++) a[i] = As4[(r0 + i) * 32 + ga];
#pragma unroll
            for (int j = 0; j < 4; j++) b[j] = As4[(c0 + j) * 32 + gb];
#pragma unroll
            for (int i = 0; i < 4; i++)
#pragma unroll
                for (int j = 0; j < 4; j++)
                    acc[i][j] += a[i].x*b[j].x + a[i].y*b[j].y + a[i].z*b[j].z + a[i].w*b[j].w;
        }
        __syncthreads();    // done reading As; safe to reuse as scratch below
#pragma unroll
        for (int i = 0; i < 4; i++) {
            int row = r0 + i;
            *(float4*)&Bout[row * 128 + c0] = make_float4(acc[i][0], acc[i][1], acc[i][2], acc[i][3]);
#pragma unroll
            for (int j = 0; j < 4; j++) {
                fp += acc[i][j] * acc[i][j];
                if (row == c0 + j) tp += acc[i][j];
            }
        }
    }
    for (int o = 32; o > 0; o >>= 1) { fp += __shfl_down(fp, o, 64); tp += __shfl_down(tp, o, 64); }
    int wid = tid >> 6, lane = tid & 63;
    __syncthreads();
    if (lane == 0) { As[wid] = fp; As[8 + wid] = tp; }
    __syncthreads();
    if (tid == 0) {
        atomicAdd(&ws[FRO2I(stage + 1, band)], As[0] + As[1] + As[2] + As[3]);
        atomicAdd(&ws[TRI(stage + 1, band)],   As[8] + As[9] + As[10] + As[11]);
        if (blockIdx.x == 0) ws[FLAGI(stage + 1, band)] = collapsed ? 1.f : 0.f;
    }
}

// ---------------- subspace iteration + Rayleigh-Ritz (parallelized) ----------------
// V,W stored column-major in LDS with row stride 136 (float4-aligned, bank-spread).
__global__ __launch_bounds__(256) void k_sub(float* __restrict__ ws, int titer) {
    int band = blockIdx.x, tid = threadIdx.x;
    const float* Ab = ws + A0_OFF + (size_t)band * GSZ;
    __shared__ __align__(16) float VcS[8 * 136];
    __shared__ __align__(16) float WcS[8 * 136];
    __shared__ float LchS[64], invdS[8], B8S[64], E8S[64];
    __shared__ int idx3S[3];

    if (titer == 0) {
        for (int idx = tid; idx < 1024; idx += 256) {
            uint32_t h = (uint32_t)(idx + band * 1024 + 7) * 2654435761u;
            h ^= h >> 15; h *= 0x2c1b3c6du; h ^= h >> 12;
            VcS[(idx >> 7) * 136 + (idx & 127)] = ((float)(h & 0xFFFF) / 32768.0f) - 1.0f;
        }
    } else {
        for (int idx = tid; idx < 1024; idx += 256)
            VcS[(idx >> 7) * 136 + (idx & 127)] = ws[VW_OFF + band * 1024 + idx];
    }
    __syncthreads();

    int c = tid & 127, sq = tid >> 7;           // A*V mapping
    int r8 = tid >> 3, s8 = tid & 7;            // 8x8 mappings (tid<64)
    int steps = (titer == 0) ? 8 : 4;

    for (int step = 0; step <= steps; step++) {
        // ---- W = A * V : thread (c,sq) computes W[c][sq*4 .. sq*4+3].
        // Accumulate over A rows (A symmetric) -> coalesced global reads.
        {
            const float* V0 = VcS + (sq * 4 + 0) * 136;
            const float* V1 = VcS + (sq * 4 + 1) * 136;
            const float* V2 = VcS + (sq * 4 + 2) * 136;
            const float* V3 = VcS + (sq * 4 + 3) * 136;
            float a0 = 0.f, a1 = 0.f, a2 = 0.f, a3 = 0.f;
            for (int k = 0; k < 128; k += 4) {
                float g0 = Ab[(k + 0) * 128 + c];
                float g1 = Ab[(k + 1) * 128 + c];
                float g2 = Ab[(k + 2) * 128 + c];
                float g3 = Ab[(k + 3) * 128 + c];
                float4 v0 = *(const float4*)&V0[k];
                float4 v1 = *(const float4*)&V1[k];
                float4 v2 = *(const float4*)&V2[k];
                float4 v3 = *(const float4*)&V3[k];
                a0 += g0 * v0.x + g1 * v0.y + g2 * v0.z + g3 * v0.w;
                a1 += g0 * v1.x + g1 * v1.y + g2 * v1.z + g3 * v1.w;
                a2 += g0 * v2.x + g1 * v2.y + g2 * v2.z + g3 * v2.w;
                a3 += g0 * v3.x + g1 * v3.y + g2 * v3.z + g3 * v3.w;
            }
            WcS[(sq * 4 + 0) * 136 + c] = a0;
            WcS[(sq * 4 + 1) * 136 + c] = a1;
            WcS[(sq * 4 + 2) * 136 + c] = a2;
            WcS[(sq * 4 + 3) * 136 + c] = a3;
        }
        __syncthreads();
        if (step == steps) break;

        // ---- CholQR: M = W^T W (wave 0), Cholesky in registers via shuffles
        if (tid < 64) {
            const float* wr = WcS + r8 * 136;
            const float* wc = WcS + s8 * 136;
            float m = 0.f;
            for (int k = 0; k < 128; k += 4) {
                float4 p = *(const float4*)&wr[k];
                float4 q = *(const float4*)&wc[k];
                m += p.x * q.x + p.y * q.y + p.z * q.z + p.w * q.w;
            }
            float t = (r8 == s8) ? m : 0.f;
#pragma unroll
            for (int o = 1; o < 64; o <<= 1) t += __shfl_xor(t, o, 64);
            float eps = 1e-12f * t + 1e-35f;
            float v = m;
#pragma unroll
            for (int j = 0; j < 8; j++) {
                float dj = __shfl(v, j * 9, 64);
                dj = fmaxf(dj, eps);
                float lj = sqrtf(dj);
                float inv = 1.f / lj;
                if (s8 == j) v = (r8 == j) ? lj : (r8 > j ? v * inv : v);
                float Lr = __shfl(v, r8 * 8 + j, 64);
                float Ls = __shfl(v, s8 * 8 + j, 64);
                if (r8 > j && s8 > j) v -= Lr * Ls;
                if (tid == j) invdS[j] = inv;
            }
            LchS[tid] = v;
        }
        __syncthreads();
        // ---- backsolve V = W L^-T (rows in parallel, tid<128)
        if (tid < 128) {
            float w[8], vv[8];
#pragma unroll
            for (int s = 0; s < 8; s++) w[s] = WcS[s * 136 + tid];
#pragma unroll
            for (int s = 0; s < 8; s++) {
                float t2 = w[s];
                for (int j = 0; j < s; j++) t2 -= vv[j] * LchS[s * 8 + j];
                vv[s] = t2 * invdS[s];
                VcS[s * 136 + tid] = vv[s];
            }
        }
        __syncthreads();
    }

    // ---- Rayleigh-Ritz: B8 = V^T (A V) (wave 0)
    if (tid < 64) {
        const float* vr = VcS + r8 * 136;
        const float* wc = WcS + s8 * 136;
        float m = 0.f;
        for (int k = 0; k < 128; k += 4) {
            float4 p = *(const float4*)&vr[k];
            float4 q = *(const float4*)&wc[k];
            m += p.x * q.x + p.y * q.y + p.z * q.z + p.w * q.w;
        }
        B8S[tid] = m;
        E8S[tid] = (r8 == s8) ? 1.f : 0.f;
    }
    __syncthreads();
    if (tid < 64 && r8 < s8) {      // symmetrize
        float a = B8S[r8 * 8 + s8], b = B8S[s8 * 8 + r8];
        float mm = 0.5f * (a + b);
        B8S[r8 * 8 + s8] = mm; B8S[s8 * 8 + r8] = mm;
    }
    __syncthreads();

    // ---- wave-synchronous parallel Jacobi (wave 0 only; in-order LDS pipe)
    if (tid < 64) {
        volatile float* vB = B8S;
        volatile float* vE = E8S;
        for (int sweep = 0; sweep < 6; sweep++) {
            for (int rd = 0; rd < 7; rd++) {
                // round-robin pairing: 7 fixed, 0..6 rotate
                int pr = (r8 == 7) ? rd : ((r8 == rd) ? 7 : (2 * rd + 7 - r8) % 7);
                int pc = (s8 == 7) ? rd : ((s8 == rd) ? 7 : (2 * rd + 7 - s8) % 7);
                int P = min(r8, pr), Q = max(r8, pr);
                int Pc = min(s8, pc), Qc = max(s8, pc);
                // params from pre-round B (both row-pair and col-pair)
                float app = vB[P * 8 + P], aqq = vB[Q * 8 + Q], apq = vB[P * 8 + Q];
                float cR, sR;
                if (fabsf(apq) < 1e-28f) { cR = 1.f; sR = 0.f; }
                else {
                    float tau = (aqq - app) / (2.f * apq);
                    float tt = ((tau >= 0.f) ? 1.f : -1.f) / (fabsf(tau) + sqrtf(1.f + tau * tau));
                    cR = rsqrtf(1.f + tt * tt); sR = tt * cR;
                }
                float ap2 = vB[Pc * 8 + Pc], aq2 = vB[Qc * 8 + Qc], apq2 = vB[Pc * 8 + Qc];
                float cC, sC;
                if (fabsf(apq2) < 1e-28f) { cC = 1.f; sC = 0.f; }
                else {
                    float tau = (aq2 - ap2) / (2.f * apq2);
                    float tt = ((tau >= 0.f) ? 1.f : -1.f) / (fabsf(tau) + sqrtf(1.f + tau * tau));
                    cC = rsqrtf(1.f + tt * tt); sC = tt * cC;
                }
                // row phase: B[P][k]' = c*B[P][k] - s*B[Q][k]; B[Q][k]' = s*B[P][k] + c*B[Q][k]
                float ov = vB[r8 * 8 + s8], tv = vB[pr * 8 + s8];
                float nv = (r8 < pr) ? (cR * ov - sR * tv) : (sR * tv + cR * ov);
                vB[r8 * 8 + s8] = nv;
                // col phase (same rotation params, post-row values)
                float o2 = vB[r8 * 8 + s8], t2 = vB[r8 * 8 + pc];
                float n2 = (s8 < pc) ? (cC * o2 - sC * t2) : (sC * t2 + cC * o2);
                vB[r8 * 8 + s8] = n2;
                // eigenvector accumulation: E <- E * J (col rotations)
                float e1 = vE[r8 * 8 + s8], e2 = vE[r8 * 8 + pc];
                float ne = (s8 < pc) ? (cC * e1 - sC * e2) : (sC * e2 + cC * e1);
                vE[r8 * 8 + s8] = ne;
            }
        }
        if (tid == 0) {
            int used = 0;
            for (int r = 0; r < 3; r++) {
                int best = 0; float bv = -1e38f;
                for (int s = 0; s < 8; s++)
                    if (!(used & (1 << s)) && vB[s * 9] > bv) { bv = vB[s * 9]; best = s; }
                used |= 1 << best;
                idx3S[r] = best;
            }
        }
    }
    __syncthreads();

    // ---- U = V * E[:, idx3], warm-start save
    if (tid < 128) {
        float e[3][8];
#pragma unroll
        for (int r = 0; r < 3; r++)
#pragma unroll
            for (int s = 0; s < 8; s++) e[r][s] = E8S[s * 8 + idx3S[r]];
        float vcl[8];
#pragma unroll
        for (int s = 0; s < 8; s++) vcl[s] = VcS[s * 136 + tid];
#pragma unroll
        for (int r = 0; r < 3; r++) {
            float u = 0.f;
#pragma unroll
            for (int s = 0; s < 8; s++) u += vcl[s] * e[r][s];
            ws[U3_OFF + band * 384 + tid * 3 + r] = u;
        }
#pragma unroll
        for (int s = 0; s < 8; s++) ws[VW_OFF + band * 1024 + s * 128 + tid] = vcl[s];
    }
}

// ---------------- UtL = U^T L ----------------
__global__ __launch_bounds__(256) void k_utl(float* __restrict__ ws) {
    int band = blockIdx.y, xc = blockIdx.x, tid = threadIdx.x;
    __shared__ float Ul[128][3];
    if (tid < 128) {
        Ul[tid][0] = ws[U3_OFF + band * 384 + tid * 3 + 0];
        Ul[tid][1] = ws[U3_OFF + band * 384 + tid * 3 + 1];
        Ul[tid][2] = ws[U3_OFF + band * 384 + tid * 3 + 2];
    }
    __syncthreads();
    int n0 = xc * 512;
    const float* Lb = ws + L_OFF + (size_t)band * CHN * NPIX;
    float a0 = 0, a1 = 0, a2 = 0, b0 = 0, b1 = 0, b2 = 0;
    for (int cc = 0; cc < 128; cc++) {
        float u0 = Ul[cc][0], u1 = Ul[cc][1], u2 = Ul[cc][2];
        float la = Lb[(size_t)cc * NPIX + n0 + tid];
        float lb = Lb[(size_t)cc * NPIX + n0 + 256 + tid];
        a0 += u0 * la; a1 += u1 * la; a2 += u2 * la;
        b0 += u0 * lb; b1 += u1 * lb; b2 += u2 * lb;
    }
    float* UtL = ws + UTL_OFF + (size_t)band * 3 * NPIX;
    UtL[0 * NPIX + n0 + tid] = a0;
    UtL[1 * NPIX + n0 + tid] = a1;
    UtL[2 * NPIX + n0 + tid] = a2;
    UtL[0 * NPIX + n0 + 256 + tid] = b0;
    UtL[1 * NPIX + n0 + 256 + tid] = b1;
    UtL[2 * NPIX + n0 + 256 + tid] = b2;
}

// ---------------- update: UV, losses, L_new ----------------
__global__ __launch_bounds__(256) void k_update(const float* __restrict__ x,
                                                const float* __restrict__ W,
                                                const float* __restrict__ xg,
                                                float* __restrict__ out,
                                                float* __restrict__ ws,
                                                float alphapow, int writeUV, int titer) {
    int gid = blockIdx.x * 256 + threadIdx.x;   // 8192*256
    int i0 = gid * 8;
    int band = i0 >> 19;
    int crow = (i0 >> 12) & 127;
    int n0 = i0 & 4095;
    double sw = *(const double*)ws;
    float rho = 0.5f * (float)(sw / (double)NTOT) * alphapow;

    const float* UtL = ws + UTL_OFF + (size_t)band * 3 * NPIX;
    float u0 = ws[U3_OFF + band * 384 + crow * 3 + 0];
    float u1 = ws[U3_OFF + band * 384 + crow * 3 + 1];
    float u2 = ws[U3_OFF + band * 384 + crow * 3 + 2];

    float xv[8], wv[8], gv[8], t0[8], t1[8], t2[8];
    *(float4*)&xv[0] = *(const float4*)(x + i0);     *(float4*)&xv[4] = *(const float4*)(x + i0 + 4);
    *(float4*)&wv[0] = *(const float4*)(W + i0);     *(float4*)&wv[4] = *(const float4*)(W + i0 + 4);
    *(float4*)&gv[0] = *(const float4*)(xg + i0);    *(float4*)&gv[4] = *(const float4*)(xg + i0 + 4);
    *(float4*)&t0[0] = *(const float4*)(UtL + n0);            *(float4*)&t0[4] = *(const float4*)(UtL + n0 + 4);
    *(float4*)&t1[0] = *(const float4*)(UtL + NPIX + n0);     *(float4*)&t1[4] = *(const float4*)(UtL + NPIX + n0 + 4);
    *(float4*)&t2[0] = *(const float4*)(UtL + 2 * NPIX + n0); *(float4*)&t2[4] = *(const float4*)(UtL + 2 * NPIX + n0 + 4);

    float lf = 0.f, ll = 0.f;
    float ln[8], uvv[8];
#pragma unroll
    for (int e = 0; e < 8; e++) {
        float uv = u0 * t0[e] + u1 * t1[e] + u2 * t2[e];
        uvv[e] = uv;
        float d = uv - xv[e];
        lf += wv[e] * d * d;
        float dg = uv - gv[e];
        ll += dg * dg;
        float mu = rho / (wv[e] + rho);
        ln[e] = xv[e] + mu * d;
    }
    float* Lp = ws + L_OFF;
    *(float4*)(Lp + i0)     = *(float4*)&ln[0];
    *(float4*)(Lp + i0 + 4) = *(float4*)&ln[4];
    if (writeUV) {
        *(float4*)(out + i0)     = *(float4*)&uvv[0];
        *(float4*)(out + i0 + 4) = *(float4*)&uvv[4];
    }
    for (int o = 32; o > 0; o >>= 1) { lf += __shfl_down(lf, o, 64); ll += __shfl_down(ll, o, 64); }
    __shared__ float red[16];
    int wid = threadIdx.x >> 6, lane = threadIdx.x & 63;
    if (lane == 0) { red[wid] = lf; red[8 + wid] = ll; }
    __syncthreads();
    if (threadIdx.x == 0) {
        float a = red[0] + red[1] + red[2] + red[3];
        float b = red[8] + red[9] + red[10] + red[11];
        atomicAdd((double*)ws + 1 + titer,  (double)a);
        atomicAdd((double*)ws + 11 + titer, (double)b);
    }
}

// ---------------- finalize losses ----------------
__global__ void k_final(float* __restrict__ out, const float* __restrict__ ws) {
    int tid = threadIdx.x;
    const double* d = (const double*)ws;
    if (tid < 10)       out[NTOT + tid] = (float)(d[1 + tid] / (double)NTOT);
    else if (tid < 20)  out[NTOT + tid] = (float)(d[11 + (tid - 10)] / (double)NTOT);
}

extern "C" void kernel_launch(void* const* d_in, const int* in_sizes, int n_in,
                              void* d_out, int out_size, void* d_ws, size_t ws_size,
                              hipStream_t stream) {
    const float* x  = (const float*)d_in[0];
    const float* W  = (const float*)d_in[1];
    const float* xg = (const float*)d_in[2];
    float* out = (float*)d_out;
    float* ws = (float*)d_ws;

    hipMemsetAsync(d_ws, 0, 4096, stream);   // zero scalar/accumulator block
    k_init<<<2048, 256, 0, stream>>>(x, W, ws);

    float ap = 1.0f;
    for (int t = 0; t < 10; t++) {
        k_gram<<<dim3(8, 32), 256, 0, stream>>>(ws);
        k_reduceG<<<dim3(8, 32), 256, 0, stream>>>(ws);
        for (int j = 0; j < KSQ; j++) {
            int inOff  = (j & 1) ? A1_OFF : A0_OFF;
            int outOff = (j & 1) ? A0_OFF : A1_OFF;
            k_sq<<<dim3(4, 32), 256, 0, stream>>>(ws, inOff, outOff, j);
        }
        k_sub<<<32, 256, 0, stream>>>(ws, t);
        k_utl<<<dim3(8, 32), 256, 0, stream>>>(ws);
        k_update<<<8192, 256, 0, stream>>>(x, W, xg, out, ws, ap, (t == 9) ? 1 : 0, t);
        ap *= 1.05f;
    }
    k_final<<<1, 64, 0, stream>>>(out, ws);
}

// Round 4
// 3003.010 us; speedup vs baseline: 2.1424x; 1.1875x over previous
//
#include <hip/hip_runtime.h>
#include <stdint.h>

#define BANDS 32
#define CHN   128
#define NPIX  4096
#define NTOT  16777216          // 32*128*4096
#define GSZ   16384             // 128*128
#define KSQ   6                 // squaring stages (G -> G^64, collapse-guarded)

// ---------------- ws layout (float indices) ----------------
// bytes [0..168): doubles: [0]=sumW, [1..10]=lossF acc, [11..20]=loss acc
// floats [64..): per-band/ per-stage scalars
#define L_OFF    1024
#define GP_OFF   (L_OFF + NTOT)                  // 32*8*16384 gram partials
#define A0_OFF   (GP_OFF + BANDS*8*GSZ)
#define A1_OFF   (A0_OFF + BANDS*GSZ)
#define U3_OFF   (A1_OFF + BANDS*GSZ)            // 32*128*3
#define VW_OFF   (U3_OFF + BANDS*CHN*3)          // 32*128*8 warm-start basis

__device__ __forceinline__ int FRO2I(int st, int b){ return 64  + st*32 + b; }
__device__ __forceinline__ int TRI  (int st, int b){ return 300 + st*32 + b; }
__device__ __forceinline__ int FLAGI(int st, int b){ return 540 + st*32 + b; }

// ---------------- init: L = x, sumW reduction ----------------
__global__ __launch_bounds__(256) void k_init(const float* __restrict__ x,
                                              const float* __restrict__ W,
                                              float* __restrict__ ws) {
    int gid = blockIdx.x * 256 + threadIdx.x;       // 2048*256 threads
    const float4* x4 = (const float4*)x;
    const float4* w4 = (const float4*)W;
    float4* L4 = (float4*)(ws + L_OFF);
    float s = 0.f;
#pragma unroll
    for (int i = 0; i < 8; i++) {
        int idx = gid + i * 524288;                 // NTOT/4 = 4194304
        float4 xv = x4[idx];
        float4 wv = w4[idx];
        L4[idx] = xv;
        s += wv.x + wv.y + wv.z + wv.w;
    }
    for (int o = 32; o > 0; o >>= 1) s += __shfl_down(s, o, 64);
    __shared__ float red[4];
    int wid = threadIdx.x >> 6, lane = threadIdx.x & 63;
    if (lane == 0) red[wid] = s;
    __syncthreads();
    if (threadIdx.x == 0) {
        float t = red[0] + red[1] + red[2] + red[3];
        atomicAdd((double*)ws, (double)t);
    }
}

// ---------------- gram: partial G[b] = L L^T, split-K 8 ----------------
__global__ __launch_bounds__(256) void k_gram(float* __restrict__ ws) {
    int band = blockIdx.y, kc = blockIdx.x, tid = threadIdx.x;
    if (kc == 0) {   // zero stage-0 scalars for the reduce kernel's atomics
        if (tid == 0) ws[FRO2I(0, band)] = 0.f;
        if (tid == 1) ws[TRI(0, band)]   = 0.f;
        if (tid == 2) ws[FLAGI(0, band)] = 0.f;
    }
    __shared__ __align__(16) float Lt[16][132];     // [kk][c], padded
    const float* Lb = ws + L_OFF + (size_t)band * CHN * NPIX;
    int k0 = kc * 512;
    int ty = tid >> 4, tx = tid & 15;
    float acc[8][8];
#pragma unroll
    for (int i = 0; i < 8; i++)
#pragma unroll
        for (int j = 0; j < 8; j++) acc[i][j] = 0.f;

    int lc = tid >> 1, lk = (tid & 1) * 8;
    for (int t = 0; t < 32; t++) {
        int kb = k0 + t * 16;
        const float* src = Lb + (size_t)lc * NPIX + kb + lk;
        float4 v0 = *(const float4*)(src);
        float4 v1 = *(const float4*)(src + 4);
        __syncthreads();
        Lt[lk + 0][lc] = v0.x; Lt[lk + 1][lc] = v0.y;
        Lt[lk + 2][lc] = v0.z; Lt[lk + 3][lc] = v0.w;
        Lt[lk + 4][lc] = v1.x; Lt[lk + 5][lc] = v1.y;
        Lt[lk + 6][lc] = v1.z; Lt[lk + 7][lc] = v1.w;
        __syncthreads();
#pragma unroll
        for (int kk = 0; kk < 16; kk++) {
            float4 a0 = *(const float4*)&Lt[kk][ty * 8];
            float4 a1 = *(const float4*)&Lt[kk][ty * 8 + 4];
            float4 b0 = *(const float4*)&Lt[kk][tx * 8];
            float4 b1 = *(const float4*)&Lt[kk][tx * 8 + 4];
            float a[8] = {a0.x,a0.y,a0.z,a0.w,a1.x,a1.y,a1.z,a1.w};
            float b[8] = {b0.x,b0.y,b0.z,b0.w,b1.x,b1.y,b1.z,b1.w};
#pragma unroll
            for (int i = 0; i < 8; i++)
#pragma unroll
                for (int j = 0; j < 8; j++) acc[i][j] += a[i] * b[j];
        }
    }
    float* Gp = ws + GP_OFF + (size_t)(band * 8 + kc) * GSZ;
#pragma unroll
    for (int i = 0; i < 8; i++) {
        int row = ty * 8 + i;
        *(float4*)&Gp[row * 128 + tx * 8]     = make_float4(acc[i][0], acc[i][1], acc[i][2], acc[i][3]);
        *(float4*)&Gp[row * 128 + tx * 8 + 4] = make_float4(acc[i][4], acc[i][5], acc[i][6], acc[i][7]);
    }
}

// ---------------- reduceG: sum partials -> A0, stage-0 stats ----------------
__global__ __launch_bounds__(256) void k_reduceG(float* __restrict__ ws) {
    int band = blockIdx.y, xc = blockIdx.x, tid = threadIdx.x;
    if (xc == 0 && tid < 18) {          // zero stage 1..6 scalars
        int st = 1 + tid / 3, a = tid % 3;
        int off = (a == 0) ? FRO2I(st, band) : (a == 1) ? TRI(st, band) : FLAGI(st, band);
        ws[off] = 0.f;
    }
    int e0 = xc * 2048 + tid * 8;
    float v[8];
#pragma unroll
    for (int j = 0; j < 8; j++) v[j] = 0.f;
#pragma unroll
    for (int p = 0; p < 8; p++) {
        const float4* src = (const float4*)(ws + GP_OFF + (size_t)(band * 8 + p) * GSZ + e0);
        float4 s0 = src[0], s1 = src[1];
        v[0] += s0.x; v[1] += s0.y; v[2] += s0.z; v[3] += s0.w;
        v[4] += s1.x; v[5] += s1.y; v[6] += s1.z; v[7] += s1.w;
    }
    float4* dst = (float4*)(ws + A0_OFF + (size_t)band * GSZ + e0);
    dst[0] = make_float4(v[0], v[1], v[2], v[3]);
    dst[1] = make_float4(v[4], v[5], v[6], v[7]);
    float fp = 0.f, tp = 0.f;
    int row = e0 >> 7, col0 = e0 & 127;
#pragma unroll
    for (int j = 0; j < 8; j++) {
        fp += v[j] * v[j];
        if (col0 + j == row) tp += v[j];
    }
    for (int o = 32; o > 0; o >>= 1) { fp += __shfl_down(fp, o, 64); tp += __shfl_down(tp, o, 64); }
    __shared__ float red[16];
    int wid = tid >> 6, lane = tid & 63;
    if (lane == 0) { red[wid] = fp; red[8 + wid] = tp; }
    __syncthreads();
    if (tid == 0) {
        atomicAdd(&ws[FRO2I(0, band)], red[0] + red[1] + red[2] + red[3]);
        atomicAdd(&ws[TRI(0, band)],   red[8] + red[9] + red[10] + red[11]);
    }
}

// ---------------- sq: B = (A/||A||_F)^2 with collapse guard ----------------
__global__ __launch_bounds__(256) void k_sq(float* __restrict__ ws, int inOff, int outOff, int stage) {
    __shared__ __align__(16) float As[16384];       // 64 KB exactly (reused as reduce scratch)
    int band = blockIdx.y, rb = blockIdx.x * 32, tid = threadIdx.x;
    const float* Ain = ws + inOff + (size_t)band * GSZ;
    float* Bout = ws + outOff + (size_t)band * GSZ;
    float fro2 = ws[FRO2I(stage, band)];
    float tr   = ws[TRI(stage, band)];
    float flag = ws[FLAGI(stage, band)];
    bool collapsed = (flag > 0.5f) || (tr * tr < 3.5f * fro2);
    float fp = 0.f, tp = 0.f;

    if (collapsed) {
        int base = rb * 128;
#pragma unroll
        for (int r = 0; r < 4; r++) {
            int fi = base + (tid + r * 256) * 4;
            float4 v = *(const float4*)(Ain + fi);
            *(float4*)(Bout + fi) = v;
            fp += v.x*v.x + v.y*v.y + v.z*v.z + v.w*v.w;
            int row = fi >> 7, col0 = fi & 127, e = row - col0;
            if (e >= 0 && e < 4) tp += (&v.x)[e];
        }
    } else {
        float scale = rsqrtf(fro2 + 1e-30f);
        const float4* Ain4 = (const float4*)Ain;
        float4* As4 = (float4*)As;
#pragma unroll
        for (int rep = 0; rep < 16; rep++) {
            int fi4 = rep * 256 + tid;              // float4 index
            int c = fi4 >> 5, g = fi4 & 31;
            float4 v = Ain4[fi4];
            v.x *= scale; v.y *= scale; v.z *= scale; v.w *= scale;
            As4[c * 32 + (g ^ (c >> 2))] = v;
        }
        __syncthreads();
        int tyy = tid >> 5, txx = tid & 31;
        int r0 = rb + tyy * 4, c0 = txx * 4;
        int rsh = r0 >> 2, csh = c0 >> 2;
        float acc[4][4];
#pragma unroll
        for (int i = 0; i < 4; i++)
#pragma unroll
            for (int j = 0; j < 4; j++) acc[i][j] = 0.f;
#pragma unroll 4
        for (int g = 0; g < 32; g++) {
            float4 a[4], b[4];
            int ga = g ^ rsh, gb = g ^ csh;
#pragma unroll
            for (int i = 0; i < 4; i++) a[i] = As4[(r0 + i) * 32 + ga];
#pragma unroll
            for (int j = 0; j < 4; j++) b[j] = As4[(c0 + j) * 32 + gb];
#pragma unroll
            for (int i = 0; i < 4; i++)
#pragma unroll
                for (int j = 0; j < 4; j++)
                    acc[i][j] += a[i].x*b[j].x + a[i].y*b[j].y + a[i].z*b[j].z + a[i].w*b[j].w;
        }
        __syncthreads();    // done reading As; safe to reuse as scratch below
#pragma unroll
        for (int i = 0; i < 4; i++) {
            int row = r0 + i;
            *(float4*)&Bout[row * 128 + c0] = make_float4(acc[i][0], acc[i][1], acc[i][2], acc[i][3]);
#pragma unroll
            for (int j = 0; j < 4; j++) {
                fp += acc[i][j] * acc[i][j];
                if (row == c0 + j) tp += acc[i][j];
            }
        }
    }
    for (int o = 32; o > 0; o >>= 1) { fp += __shfl_down(fp, o, 64); tp += __shfl_down(tp, o, 64); }
    int wid = tid >> 6, lane = tid & 63;
    __syncthreads();
    if (lane == 0) { As[wid] = fp; As[8 + wid] = tp; }
    __syncthreads();
    if (tid == 0) {
        atomicAdd(&ws[FRO2I(stage + 1, band)], As[0] + As[1] + As[2] + As[3]);
        atomicAdd(&ws[TRI(stage + 1, band)],   As[8] + As[9] + As[10] + As[11]);
        if (blockIdx.x == 0) ws[FLAGI(stage + 1, band)] = collapsed ? 1.f : 0.f;
    }
}

// ---------------- subspace iteration + Rayleigh-Ritz (parallelized) ----------------
// V,W stored column-major in LDS with row stride 136 (float4-aligned, bank-spread).
__global__ __launch_bounds__(256) void k_sub(float* __restrict__ ws, int titer) {
    int band = blockIdx.x, tid = threadIdx.x;
    const float* Ab = ws + A0_OFF + (size_t)band * GSZ;
    __shared__ __align__(16) float VcS[8 * 136];
    __shared__ __align__(16) float WcS[8 * 136];
    __shared__ float LchS[64], invdS[8], B8S[64], E8S[64];
    __shared__ int idx3S[3];

    if (titer == 0) {
        for (int idx = tid; idx < 1024; idx += 256) {
            uint32_t h = (uint32_t)(idx + band * 1024 + 7) * 2654435761u;
            h ^= h >> 15; h *= 0x2c1b3c6du; h ^= h >> 12;
            VcS[(idx >> 7) * 136 + (idx & 127)] = ((float)(h & 0xFFFF) / 32768.0f) - 1.0f;
        }
    } else {
        for (int idx = tid; idx < 1024; idx += 256)
            VcS[(idx >> 7) * 136 + (idx & 127)] = ws[VW_OFF + band * 1024 + idx];
    }
    __syncthreads();

    int c = tid & 127, sq = tid >> 7;           // A*V mapping
    int r8 = tid >> 3, s8 = tid & 7;            // 8x8 mappings (tid<64)
    int steps = (titer == 0) ? 8 : 4;

    for (int step = 0; step <= steps; step++) {
        // ---- W = A * V : thread (c,sq) computes W[c][sq*4 .. sq*4+3].
        {
            const float* V0 = VcS + (sq * 4 + 0) * 136;
            const float* V1 = VcS + (sq * 4 + 1) * 136;
            const float* V2 = VcS + (sq * 4 + 2) * 136;
            const float* V3 = VcS + (sq * 4 + 3) * 136;
            float a0 = 0.f, a1 = 0.f, a2 = 0.f, a3 = 0.f;
            for (int k = 0; k < 128; k += 4) {
                float g0 = Ab[(k + 0) * 128 + c];
                float g1 = Ab[(k + 1) * 128 + c];
                float g2 = Ab[(k + 2) * 128 + c];
                float g3 = Ab[(k + 3) * 128 + c];
                float4 v0 = *(const float4*)&V0[k];
                float4 v1 = *(const float4*)&V1[k];
                float4 v2 = *(const float4*)&V2[k];
                float4 v3 = *(const float4*)&V3[k];
                a0 += g0 * v0.x + g1 * v0.y + g2 * v0.z + g3 * v0.w;
                a1 += g0 * v1.x + g1 * v1.y + g2 * v1.z + g3 * v1.w;
                a2 += g0 * v2.x + g1 * v2.y + g2 * v2.z + g3 * v2.w;
                a3 += g0 * v3.x + g1 * v3.y + g2 * v3.z + g3 * v3.w;
            }
            WcS[(sq * 4 + 0) * 136 + c] = a0;
            WcS[(sq * 4 + 1) * 136 + c] = a1;
            WcS[(sq * 4 + 2) * 136 + c] = a2;
            WcS[(sq * 4 + 3) * 136 + c] = a3;
        }
        __syncthreads();
        if (step == steps) break;

        // ---- CholQR: M = W^T W (wave 0), Cholesky in registers via shuffles
        if (tid < 64) {
            const float* wr = WcS + r8 * 136;
            const float* wc = WcS + s8 * 136;
            float m = 0.f;
            for (int k = 0; k < 128; k += 4) {
                float4 p = *(const float4*)&wr[k];
                float4 q = *(const float4*)&wc[k];
                m += p.x * q.x + p.y * q.y + p.z * q.z + p.w * q.w;
            }
            float t = (r8 == s8) ? m : 0.f;
#pragma unroll
            for (int o = 1; o < 64; o <<= 1) t += __shfl_xor(t, o, 64);
            float eps = 1e-12f * t + 1e-35f;
            float v = m;
#pragma unroll
            for (int j = 0; j < 8; j++) {
                float dj = __shfl(v, j * 9, 64);
                dj = fmaxf(dj, eps);
                float lj = sqrtf(dj);
                float inv = 1.f / lj;
                if (s8 == j) v = (r8 == j) ? lj : (r8 > j ? v * inv : v);
                float Lr = __shfl(v, r8 * 8 + j, 64);
                float Ls = __shfl(v, s8 * 8 + j, 64);
                if (r8 > j && s8 > j) v -= Lr * Ls;
                if (tid == j) invdS[j] = inv;
            }
            LchS[tid] = v;
        }
        __syncthreads();
        // ---- backsolve V = W L^-T (rows in parallel, tid<128)
        if (tid < 128) {
            float w[8], vv[8];
#pragma unroll
            for (int s = 0; s < 8; s++) w[s] = WcS[s * 136 + tid];
#pragma unroll
            for (int s = 0; s < 8; s++) {
                float t2 = w[s];
                for (int j = 0; j < s; j++) t2 -= vv[j] * LchS[s * 8 + j];
                vv[s] = t2 * invdS[s];
                VcS[s * 136 + tid] = vv[s];
            }
        }
        __syncthreads();
    }

    // ---- Rayleigh-Ritz: B8 = V^T (A V) (wave 0)
    if (tid < 64) {
        const float* vr = VcS + r8 * 136;
        const float* wc = WcS + s8 * 136;
        float m = 0.f;
        for (int k = 0; k < 128; k += 4) {
            float4 p = *(const float4*)&vr[k];
            float4 q = *(const float4*)&wc[k];
            m += p.x * q.x + p.y * q.y + p.z * q.z + p.w * q.w;
        }
        B8S[tid] = m;
        E8S[tid] = (r8 == s8) ? 1.f : 0.f;
    }
    __syncthreads();
    if (tid < 64 && r8 < s8) {      // symmetrize
        float a = B8S[r8 * 8 + s8], b = B8S[s8 * 8 + r8];
        float mm = 0.5f * (a + b);
        B8S[r8 * 8 + s8] = mm; B8S[s8 * 8 + r8] = mm;
    }
    __syncthreads();

    // ---- wave-synchronous parallel Jacobi (wave 0 only; in-order LDS pipe)
    if (tid < 64) {
        volatile float* vB = B8S;
        volatile float* vE = E8S;
        for (int sweep = 0; sweep < 6; sweep++) {
            for (int rd = 0; rd < 7; rd++) {
                int pr = (r8 == 7) ? rd : ((r8 == rd) ? 7 : (2 * rd + 7 - r8) % 7);
                int pc = (s8 == 7) ? rd : ((s8 == rd) ? 7 : (2 * rd + 7 - s8) % 7);
                int P = min(r8, pr), Q = max(r8, pr);
                int Pc = min(s8, pc), Qc = max(s8, pc);
                float app = vB[P * 8 + P], aqq = vB[Q * 8 + Q], apq = vB[P * 8 + Q];
                float cR, sR;
                if (fabsf(apq) < 1e-28f) { cR = 1.f; sR = 0.f; }
                else {
                    float tau = (aqq - app) / (2.f * apq);
                    float tt = ((tau >= 0.f) ? 1.f : -1.f) / (fabsf(tau) + sqrtf(1.f + tau * tau));
                    cR = rsqrtf(1.f + tt * tt); sR = tt * cR;
                }
                float ap2 = vB[Pc * 8 + Pc], aq2 = vB[Qc * 8 + Qc], apq2 = vB[Pc * 8 + Qc];
                float cC, sC;
                if (fabsf(apq2) < 1e-28f) { cC = 1.f; sC = 0.f; }
                else {
                    float tau = (aq2 - ap2) / (2.f * apq2);
                    float tt = ((tau >= 0.f) ? 1.f : -1.f) / (fabsf(tau) + sqrtf(1.f + tau * tau));
                    cC = rsqrtf(1.f + tt * tt); sC = tt * cC;
                }
                float ov = vB[r8 * 8 + s8], tv = vB[pr * 8 + s8];
                float nv = (r8 < pr) ? (cR * ov - sR * tv) : (sR * tv + cR * ov);
                vB[r8 * 8 + s8] = nv;
                float o2 = vB[r8 * 8 + s8], t2 = vB[r8 * 8 + pc];
                float n2 = (s8 < pc) ? (cC * o2 - sC * t2) : (sC * t2 + cC * o2);
                vB[r8 * 8 + s8] = n2;
                float e1 = vE[r8 * 8 + s8], e2 = vE[r8 * 8 + pc];
                float ne = (s8 < pc) ? (cC * e1 - sC * e2) : (sC * e2 + cC * e1);
                vE[r8 * 8 + s8] = ne;
            }
        }
        if (tid == 0) {
            int used = 0;
            for (int r = 0; r < 3; r++) {
                int best = 0; float bv = -1e38f;
                for (int s = 0; s < 8; s++)
                    if (!(used & (1 << s)) && vB[s * 9] > bv) { bv = vB[s * 9]; best = s; }
                used |= 1 << best;
                idx3S[r] = best;
            }
        }
    }
    __syncthreads();

    // ---- U = V * E[:, idx3], warm-start save
    if (tid < 128) {
        float e[3][8];
#pragma unroll
        for (int r = 0; r < 3; r++)
#pragma unroll
            for (int s = 0; s < 8; s++) e[r][s] = E8S[s * 8 + idx3S[r]];
        float vcl[8];
#pragma unroll
        for (int s = 0; s < 8; s++) vcl[s] = VcS[s * 136 + tid];
#pragma unroll
        for (int r = 0; r < 3; r++) {
            float u = 0.f;
#pragma unroll
            for (int s = 0; s < 8; s++) u += vcl[s] * e[r][s];
            ws[U3_OFF + band * 384 + tid * 3 + r] = u;
        }
#pragma unroll
        for (int s = 0; s < 8; s++) ws[VW_OFF + band * 1024 + s * 128 + tid] = vcl[s];
    }
}

// ---------------- fused: utl = U^T L (phase 1, LDS) + UV/losses/L_new (phase 2) ----------------
// block = (chunk xc of 256 px, band). Phase 2 writes only this block's pixels, so
// no cross-block race with other blocks' phase-1 reads (disjoint pixel sets).
__global__ __launch_bounds__(256) void k_upd(const float* __restrict__ x,
                                             const float* __restrict__ W,
                                             const float* __restrict__ xg,
                                             float* __restrict__ out,
                                             float* __restrict__ ws,
                                             float alphapow, int writeUV, int titer) {
    int band = blockIdx.y, xc = blockIdx.x, tid = threadIdx.x;
    int w = tid >> 6, lane = tid & 63;
    int n0 = xc * 256, p4 = lane * 4;
    __shared__ float Us[128][4];
    __shared__ __align__(16) float up[12][260];   // per-wave utl partials [w*3+r][px]
    __shared__ __align__(16) float um[3][260];    // reduced utl
    __shared__ float red[16];

    if (tid < 128) {
        Us[tid][0] = ws[U3_OFF + band * 384 + tid * 3 + 0];
        Us[tid][1] = ws[U3_OFF + band * 384 + tid * 3 + 1];
        Us[tid][2] = ws[U3_OFF + band * 384 + tid * 3 + 2];
    }
    __syncthreads();

    // ---- phase 1: utl[r][p] = sum_c U[c][r] * L[c][p]
    const float* Lb = ws + L_OFF + (size_t)band * CHN * NPIX;
    float4 a0 = make_float4(0.f,0.f,0.f,0.f), a1 = a0, a2 = a0;
    for (int cg = 0; cg < 32; cg++) {
        int c = cg * 4 + w;
        float4 lv = *(const float4*)(Lb + (size_t)c * NPIX + n0 + p4);
        float u0 = Us[c][0], u1 = Us[c][1], u2 = Us[c][2];
        a0.x += u0 * lv.x; a0.y += u0 * lv.y; a0.z += u0 * lv.z; a0.w += u0 * lv.w;
        a1.x += u1 * lv.x; a1.y += u1 * lv.y; a1.z += u1 * lv.z; a1.w += u1 * lv.w;
        a2.x += u2 * lv.x; a2.y += u2 * lv.y; a2.z += u2 * lv.z; a2.w += u2 * lv.w;
    }
    *(float4*)&up[w * 3 + 0][p4] = a0;
    *(float4*)&up[w * 3 + 1][p4] = a1;
    *(float4*)&up[w * 3 + 2][p4] = a2;
    __syncthreads();
    if (tid < 192) {
        int r = tid >> 6, l = (tid & 63) * 4;
        float4 s0 = *(float4*)&up[r][l];
        float4 s1 = *(float4*)&up[3 + r][l];
        float4 s2 = *(float4*)&up[6 + r][l];
        float4 s3 = *(float4*)&up[9 + r][l];
        *(float4*)&um[r][l] = make_float4(s0.x + s1.x + s2.x + s3.x,
                                          s0.y + s1.y + s2.y + s3.y,
                                          s0.z + s1.z + s2.z + s3.z,
                                          s0.w + s1.w + s2.w + s3.w);
    }
    __syncthreads();

    // ---- phase 2: stream x/W/xg, compute UV, losses, L_new (and out at t=9)
    double sw = *(const double*)ws;
    float rho = 0.5f * (float)(sw / (double)NTOT) * alphapow;
    float4 t0 = *(float4*)&um[0][p4];
    float4 t1 = *(float4*)&um[1][p4];
    float4 t2 = *(float4*)&um[2][p4];
    float lf = 0.f, ll = 0.f;
    size_t base = (size_t)band * CHN * NPIX + n0 + p4;
    float* Lp = ws + L_OFF;
#pragma unroll 2
    for (int cg = 0; cg < 32; cg++) {
        int c = cg * 4 + w;
        size_t idx = base + (size_t)c * NPIX;
        float4 xv = *(const float4*)(x + idx);
        float4 wv = *(const float4*)(W + idx);
        float4 gv = *(const float4*)(xg + idx);
        float u0 = Us[c][0], u1 = Us[c][1], u2 = Us[c][2];
        float4 uv, ln;
        uv.x = u0 * t0.x + u1 * t1.x + u2 * t2.x;
        uv.y = u0 * t0.y + u1 * t1.y + u2 * t2.y;
        uv.z = u0 * t0.z + u1 * t1.z + u2 * t2.z;
        uv.w = u0 * t0.w + u1 * t1.w + u2 * t2.w;
        float dx0 = uv.x - xv.x, dx1 = uv.y - xv.y, dx2 = uv.z - xv.z, dx3 = uv.w - xv.w;
        lf += wv.x * dx0 * dx0 + wv.y * dx1 * dx1 + wv.z * dx2 * dx2 + wv.w * dx3 * dx3;
        float g0 = uv.x - gv.x, g1 = uv.y - gv.y, g2 = uv.z - gv.z, g3 = uv.w - gv.w;
        ll += g0 * g0 + g1 * g1 + g2 * g2 + g3 * g3;
        ln.x = xv.x + (rho / (wv.x + rho)) * dx0;
        ln.y = xv.y + (rho / (wv.y + rho)) * dx1;
        ln.z = xv.z + (rho / (wv.z + rho)) * dx2;
        ln.w = xv.w + (rho / (wv.w + rho)) * dx3;
        *(float4*)(Lp + idx) = ln;
        if (writeUV) *(float4*)(out + idx) = uv;
    }
    for (int o = 32; o > 0; o >>= 1) { lf += __shfl_down(lf, o, 64); ll += __shfl_down(ll, o, 64); }
    if (lane == 0) { red[w] = lf; red[8 + w] = ll; }
    __syncthreads();
    if (tid == 0) {
        float a = red[0] + red[1] + red[2] + red[3];
        float b = red[8] + red[9] + red[10] + red[11];
        atomicAdd((double*)ws + 1 + titer,  (double)a);
        atomicAdd((double*)ws + 11 + titer, (double)b);
    }
}

// ---------------- finalize losses ----------------
__global__ void k_final(float* __restrict__ out, const float* __restrict__ ws) {
    int tid = threadIdx.x;
    const double* d = (const double*)ws;
    if (tid < 10)       out[NTOT + tid] = (float)(d[1 + tid] / (double)NTOT);
    else if (tid < 20)  out[NTOT + tid] = (float)(d[11 + (tid - 10)] / (double)NTOT);
}

extern "C" void kernel_launch(void* const* d_in, const int* in_sizes, int n_in,
                              void* d_out, int out_size, void* d_ws, size_t ws_size,
                              hipStream_t stream) {
    const float* x  = (const float*)d_in[0];
    const float* W  = (const float*)d_in[1];
    const float* xg = (const float*)d_in[2];
    float* out = (float*)d_out;
    float* ws = (float*)d_ws;

    hipMemsetAsync(d_ws, 0, 4096, stream);   // zero scalar/accumulator block
    k_init<<<2048, 256, 0, stream>>>(x, W, ws);

    float ap = 1.0f;
    for (int t = 0; t < 10; t++) {
        k_gram<<<dim3(8, 32), 256, 0, stream>>>(ws);
        k_reduceG<<<dim3(8, 32), 256, 0, stream>>>(ws);
        for (int j = 0; j < KSQ; j++) {
            int inOff  = (j & 1) ? A1_OFF : A0_OFF;
            int outOff = (j & 1) ? A0_OFF : A1_OFF;
            k_sq<<<dim3(4, 32), 256, 0, stream>>>(ws, inOff, outOff, j);
        }
        k_sub<<<32, 256, 0, stream>>>(ws, t);
        k_upd<<<dim3(16, 32), 256, 0, stream>>>(x, W, xg, out, ws, ap, (t == 9) ? 1 : 0, t);
        ap *= 1.05f;
    }
    k_final<<<1, 64, 0, stream>>>(out, ws);
}